// Round 1
// baseline (1663.363 us; speedup 1.0000x reference)
//
#include <hip/hip_runtime.h>
#include <hip/hip_bf16.h>

// Problem constants: inputs (16384, 2048) fp32, g=4 groups, d=512, N=16384 samples/group.
#define NG 4
#define DD 512
#define NN 16384
#define EPSV 1e-5f
#define GRP_ELEMS ((size_t)NN * DD)      // 8388608
#define MAT_ELEMS ((size_t)DD * DD)      // 262144

// ---------------------------------------------------------------------------
// Kernel 1: column sums  cs[g*512+d] = sum_n Z[g][n][d]
// grid (8, 32), block 256. Each block: 256 columns x 512 rows partial.
__global__ __launch_bounds__(256) void colsum_kernel(const float* __restrict__ Z,
                                                     float* __restrict__ cs) {
    int c = blockIdx.x * 256 + threadIdx.x;       // 0..2047
    int a = c >> 9;
    int d = c & 511;
    const float* p = Z + (size_t)a * GRP_ELEMS + (size_t)blockIdx.y * 512 * DD + d;
    float s = 0.f;
    #pragma unroll 8
    for (int n = 0; n < 512; ++n) s += p[(size_t)n * DD];
    atomicAdd(&cs[c], s);
}

// ---------------------------------------------------------------------------
// Kernel 2: G += Z^T Z (uncentered), split-K with atomic accumulation.
// grid (16 tiles, 8 k-chunks, 4 groups), block 256. 128x128 tile, 8x8/thread.
__global__ __launch_bounds__(256) void syrk_kernel(const float* __restrict__ Z,
                                                   float* __restrict__ Gm) {
    __shared__ float As[8][128];
    __shared__ float Bs[8][128];
    int a = blockIdx.z;
    int i0 = (blockIdx.x & 3) * 128;
    int j0 = (blockIdx.x >> 2) * 128;
    const float* Zg = Z + (size_t)a * GRP_ELEMS;
    int t  = threadIdx.x;
    int lr = t >> 5;             // 0..7  (k within chunk)
    int lc = (t & 31) << 2;      // 0..124 (col, float4)
    int tx = t & 15, ty = t >> 4;
    float acc[8][8] = {};
    int kbase = blockIdx.y * (NN / 8);   // 2048-row chunk
    for (int kc = 0; kc < NN / 8; kc += 8) {
        size_t row = (size_t)(kbase + kc + lr) * DD;
        float4 av = *(const float4*)&Zg[row + i0 + lc];
        float4 bv = *(const float4*)&Zg[row + j0 + lc];
        __syncthreads();
        *(float4*)&As[lr][lc] = av;
        *(float4*)&Bs[lr][lc] = bv;
        __syncthreads();
        #pragma unroll
        for (int kk = 0; kk < 8; ++kk) {
            float a0[8], b0[8];
            *(float4*)&a0[0] = *(const float4*)&As[kk][tx * 4];
            *(float4*)&a0[4] = *(const float4*)&As[kk][64 + tx * 4];
            *(float4*)&b0[0] = *(const float4*)&Bs[kk][ty * 4];
            *(float4*)&b0[4] = *(const float4*)&Bs[kk][64 + ty * 4];
            #pragma unroll
            for (int i = 0; i < 8; ++i)
                #pragma unroll
                for (int j = 0; j < 8; ++j)
                    acc[i][j] += a0[i] * b0[j];
        }
    }
    float* Gg = Gm + (size_t)a * MAT_ELEMS;
    #pragma unroll
    for (int i = 0; i < 8; ++i) {
        int ri = i0 + ((i < 4) ? (tx * 4 + i) : (64 + tx * 4 + (i - 4)));
        #pragma unroll
        for (int j = 0; j < 8; ++j) {
            int cj = j0 + ((j < 4) ? (ty * 4 + j) : (64 + ty * 4 + (j - 4)));
            atomicAdd(&Gg[(size_t)ri * DD + cj], acc[i][j]);
        }
    }
}

// ---------------------------------------------------------------------------
// Kernel 3: S = G - cs_i cs_j / N + eps*I  (in place); accumulate Frobenius^2.
__global__ __launch_bounds__(256) void finalize_S(float* __restrict__ S,
                                                  const float* __restrict__ cs,
                                                  float* __restrict__ nrm) {
    int a = blockIdx.z;
    size_t idx = (size_t)blockIdx.x * 256 + threadIdx.x;  // 0..262143
    int i = (int)(idx >> 9), j = (int)(idx & 511);
    const float* c = cs + a * DD;
    size_t off = (size_t)a * MAT_ELEMS + idx;
    float v = S[off] - c[i] * c[j] * (1.f / (float)NN) + (i == j ? EPSV : 0.f);
    S[off] = v;
    float ss = v * v;
    #pragma unroll
    for (int o = 32; o; o >>= 1) ss += __shfl_down(ss, o, 64);
    if ((threadIdx.x & 63) == 0) atomicAdd(&nrm[a], ss);
}

// ---------------------------------------------------------------------------
// Kernel 4: B1 = 1.5*I - 0.5 * S / nu   (nu = sqrt(nrm)); folds NS iteration 1.
__global__ __launch_bounds__(256) void init_B(float* __restrict__ B,
                                              const float* __restrict__ S,
                                              const float* __restrict__ nrm) {
    int a = blockIdx.z;
    size_t idx = (size_t)blockIdx.x * 256 + threadIdx.x;
    int i = (int)(idx >> 9), j = (int)(idx & 511);
    float inv = rsqrtf(nrm[a]);   // 1/nu
    size_t off = (size_t)a * MAT_ELEMS + idx;
    B[off] = (i == j ? 1.5f : 0.f) - 0.5f * inv * S[off];
}

// ---------------------------------------------------------------------------
// Kernel 5: batched 512^3 GEMM  C = A * B  (row-major, per group).
// grid (64, 1, 4), block 256. 64x64 tile, 4x4/thread, KT=16.
__global__ __launch_bounds__(256) void gemm512(const float* __restrict__ A,
                                               const float* __restrict__ Bm,
                                               float* __restrict__ C) {
    __shared__ float As[16][64];
    __shared__ float Bs[16][64];
    int a = blockIdx.z;
    const float* Ag = A + (size_t)a * MAT_ELEMS;
    const float* Bg = Bm + (size_t)a * MAT_ELEMS;
    float* Cg = C + (size_t)a * MAT_ELEMS;
    int i0 = (blockIdx.x & 7) * 64;
    int j0 = (blockIdx.x >> 3) * 64;
    int t = threadIdx.x;
    int ai = t >> 2, ak = (t & 3) << 2;     // A: 64 rows x 16 k
    int bk = t >> 4, bj = (t & 15) << 2;    // B: 16 k x 64 cols
    int tx = t & 15, ty = t >> 4;
    float acc[4][4] = {};
    for (int k0 = 0; k0 < DD; k0 += 16) {
        float4 av = *(const float4*)&Ag[(size_t)(i0 + ai) * DD + k0 + ak];
        float4 bv = *(const float4*)&Bg[(size_t)(k0 + bk) * DD + j0 + bj];
        __syncthreads();
        As[ak + 0][ai] = av.x; As[ak + 1][ai] = av.y;
        As[ak + 2][ai] = av.z; As[ak + 3][ai] = av.w;
        *(float4*)&Bs[bk][bj] = bv;
        __syncthreads();
        #pragma unroll
        for (int kk = 0; kk < 16; ++kk) {
            float a0[4], b0[4];
            *(float4*)&a0[0] = *(const float4*)&As[kk][tx * 4];
            *(float4*)&b0[0] = *(const float4*)&Bs[kk][ty * 4];
            #pragma unroll
            for (int i = 0; i < 4; ++i)
                #pragma unroll
                for (int j = 0; j < 4; ++j)
                    acc[i][j] += a0[i] * b0[j];
        }
    }
    #pragma unroll
    for (int i = 0; i < 4; ++i) {
        float4 v = make_float4(acc[i][0], acc[i][1], acc[i][2], acc[i][3]);
        *(float4*)&Cg[(size_t)(i0 + tx * 4 + i) * DD + j0 + ty * 4] = v;
    }
}

// Kernel 6: Bnew = 1.5*Bcur - (0.5/nu) * (A * S)   (A = B3). Same GEMM + epilogue.
__global__ __launch_bounds__(256) void gemm512_final(const float* __restrict__ A,
                                                     const float* __restrict__ Sm,
                                                     const float* __restrict__ Bcur,
                                                     const float* __restrict__ nrm,
                                                     float* __restrict__ C) {
    __shared__ float As[16][64];
    __shared__ float Bs[16][64];
    int a = blockIdx.z;
    const float* Ag = A + (size_t)a * MAT_ELEMS;
    const float* Bg = Sm + (size_t)a * MAT_ELEMS;
    const float* Pg = Bcur + (size_t)a * MAT_ELEMS;
    float* Cg = C + (size_t)a * MAT_ELEMS;
    int i0 = (blockIdx.x & 7) * 64;
    int j0 = (blockIdx.x >> 3) * 64;
    int t = threadIdx.x;
    int ai = t >> 2, ak = (t & 3) << 2;
    int bk = t >> 4, bj = (t & 15) << 2;
    int tx = t & 15, ty = t >> 4;
    float acc[4][4] = {};
    for (int k0 = 0; k0 < DD; k0 += 16) {
        float4 av = *(const float4*)&Ag[(size_t)(i0 + ai) * DD + k0 + ak];
        float4 bv = *(const float4*)&Bg[(size_t)(k0 + bk) * DD + j0 + bj];
        __syncthreads();
        As[ak + 0][ai] = av.x; As[ak + 1][ai] = av.y;
        As[ak + 2][ai] = av.z; As[ak + 3][ai] = av.w;
        *(float4*)&Bs[bk][bj] = bv;
        __syncthreads();
        #pragma unroll
        for (int kk = 0; kk < 16; ++kk) {
            float a0[4], b0[4];
            *(float4*)&a0[0] = *(const float4*)&As[kk][tx * 4];
            *(float4*)&b0[0] = *(const float4*)&Bs[kk][ty * 4];
            #pragma unroll
            for (int i = 0; i < 4; ++i)
                #pragma unroll
                for (int j = 0; j < 4; ++j)
                    acc[i][j] += a0[i] * b0[j];
        }
    }
    float scale = 0.5f * rsqrtf(nrm[a]);   // 0.5/nu
    #pragma unroll
    for (int i = 0; i < 4; ++i) {
        size_t off = (size_t)(i0 + tx * 4 + i) * DD + j0 + ty * 4;
        float4 p = *(const float4*)&Pg[off];
        float4 v = make_float4(1.5f * p.x - scale * acc[i][0],
                               1.5f * p.y - scale * acc[i][1],
                               1.5f * p.z - scale * acc[i][2],
                               1.5f * p.w - scale * acc[i][3]);
        *(float4*)&Cg[off] = v;
    }
}

// ---------------------------------------------------------------------------
// Kernel 7: out[n][i] = (sum_e Zc[n][e] * B[i][e]) / sqrt(nu)
// grid (512, 1, 4), block 256. 128x128 tile, 8x8/thread, KT=8.
__global__ __launch_bounds__(256) void wgemm_kernel(const float* __restrict__ Z,
                                                    const float* __restrict__ cs,
                                                    const float* __restrict__ Bm,
                                                    const float* __restrict__ nrm,
                                                    float* __restrict__ out) {
    __shared__ float As[8][128];
    __shared__ float Bs[8][128];
    __shared__ float Mu[DD];
    int a = blockIdx.z;
    int n0 = (blockIdx.x >> 2) * 128;
    int j0 = (blockIdx.x & 3) * 128;
    const float* Zg = Z + (size_t)a * GRP_ELEMS;
    const float* Bg = Bm + (size_t)a * MAT_ELEMS;
    int t = threadIdx.x;
    Mu[t]       = cs[a * DD + t]       * (1.f / (float)NN);
    Mu[256 + t] = cs[a * DD + 256 + t] * (1.f / (float)NN);
    __syncthreads();
    int lr = t >> 1;             // 0..127 (row)
    int lk = (t & 1) << 2;       // 0 or 4 (k within chunk, float4)
    int tx = t & 15, ty = t >> 4;
    float acc[8][8] = {};
    for (int e0 = 0; e0 < DD; e0 += 8) {
        float4 av = *(const float4*)&Zg[(size_t)(n0 + lr) * DD + e0 + lk];
        av.x -= Mu[e0 + lk + 0]; av.y -= Mu[e0 + lk + 1];
        av.z -= Mu[e0 + lk + 2]; av.w -= Mu[e0 + lk + 3];
        float4 bv = *(const float4*)&Bg[(size_t)(j0 + lr) * DD + e0 + lk];
        __syncthreads();
        As[lk + 0][lr] = av.x; As[lk + 1][lr] = av.y;
        As[lk + 2][lr] = av.z; As[lk + 3][lr] = av.w;
        Bs[lk + 0][lr] = bv.x; Bs[lk + 1][lr] = bv.y;
        Bs[lk + 2][lr] = bv.z; Bs[lk + 3][lr] = bv.w;
        __syncthreads();
        #pragma unroll
        for (int kk = 0; kk < 8; ++kk) {
            float a0[8], b0[8];
            *(float4*)&a0[0] = *(const float4*)&As[kk][tx * 4];
            *(float4*)&a0[4] = *(const float4*)&As[kk][64 + tx * 4];
            *(float4*)&b0[0] = *(const float4*)&Bs[kk][ty * 4];
            *(float4*)&b0[4] = *(const float4*)&Bs[kk][64 + ty * 4];
            #pragma unroll
            for (int i = 0; i < 8; ++i)
                #pragma unroll
                for (int j = 0; j < 8; ++j)
                    acc[i][j] += a0[i] * b0[j];
        }
    }
    float scale = rsqrtf(sqrtf(nrm[a]));   // 1/sqrt(nu)
    #pragma unroll
    for (int i = 0; i < 8; ++i) {
        int ri = n0 + ((i < 4) ? (tx * 4 + i) : (64 + tx * 4 + (i - 4)));
        size_t obase = (size_t)a * GRP_ELEMS + (size_t)ri * DD + j0;
        float4 v0 = make_float4(scale * acc[i][0], scale * acc[i][1],
                                scale * acc[i][2], scale * acc[i][3]);
        float4 v1 = make_float4(scale * acc[i][4], scale * acc[i][5],
                                scale * acc[i][6], scale * acc[i][7]);
        *(float4*)&out[obase + ty * 4] = v0;
        *(float4*)&out[obase + 64 + ty * 4] = v1;
    }
}

// ---------------------------------------------------------------------------
extern "C" void kernel_launch(void* const* d_in, const int* in_sizes, int n_in,
                              void* d_out, int out_size, void* d_ws, size_t ws_size,
                              hipStream_t stream) {
    const float* Z = (const float*)d_in[0];
    float* out = (float*)d_out;
    float* ws = (float*)d_ws;

    float* cs  = ws;                        // 2048 floats
    float* nrm = ws + 2048;                 // 4 floats
    float* S   = ws + 4096;                 // 4*512*512
    float* B0  = S  + NG * MAT_ELEMS;
    float* B1b = B0 + NG * MAT_ELEMS;
    float* B3  = B1b + NG * MAT_ELEMS;

    // zero cs, nrm, S (atomic accumulation targets)
    hipMemsetAsync(ws, 0, (4096 + NG * MAT_ELEMS) * sizeof(float), stream);

    colsum_kernel<<<dim3(8, 32), 256, 0, stream>>>(Z, cs);
    syrk_kernel<<<dim3(16, 8, NG), 256, 0, stream>>>(Z, S);
    finalize_S<<<dim3(1024, 1, NG), 256, 0, stream>>>(S, cs, nrm);
    init_B<<<dim3(1024, 1, NG), 256, 0, stream>>>(B0, S, nrm);

    float* cur = B0;
    float* nxt = B1b;
    for (int it = 0; it < 4; ++it) {   // NS iterations 2..5 (iter 1 folded in init_B)
        gemm512<<<dim3(64, 1, NG), 256, 0, stream>>>(cur, cur, nxt);        // B2 = B*B
        gemm512<<<dim3(64, 1, NG), 256, 0, stream>>>(nxt, cur, B3);         // B3 = B2*B
        gemm512_final<<<dim3(64, 1, NG), 256, 0, stream>>>(B3, S, cur, nrm, nxt);
        float* tmp = cur; cur = nxt; nxt = tmp;
    }

    wgemm_kernel<<<dim3(512, 1, NG), 256, 0, stream>>>(Z, cs, cur, nrm, out);
}

// Round 2
// 785.241 us; speedup vs baseline: 2.1183x; 2.1183x over previous
//
#include <hip/hip_runtime.h>
#include <hip/hip_bf16.h>

// Problem: inputs (16384, 2048) fp32 -> reshape (g=4, N=16384, d=512).
#define NG 4
#define DD 512
#define NN 16384
#define EPSV 1e-5f
#define GRP_ELEMS ((size_t)NN * DD)      // 8388608 = 2^23
#define MAT_ELEMS ((size_t)DD * DD)      // 262144
#define KCHUNKS 8

typedef __attribute__((ext_vector_type(8))) short bf16x8;
typedef __attribute__((ext_vector_type(4))) float f32x4;

__device__ __forceinline__ ushort f2b(float f) {
    union { float f; unsigned u; } x; x.f = f;
    unsigned r = (x.u + 0x7fffu + ((x.u >> 16) & 1u)) >> 16;
    return (ushort)r;
}
__device__ __forceinline__ float b2f(ushort u) {
    union { unsigned u; float f; } x; x.u = ((unsigned)u) << 16;
    return x.f;
}
__device__ __forceinline__ void load_lds16(const ushort* g, ushort* l) {
    __builtin_amdgcn_global_load_lds(
        (const __attribute__((address_space(1))) void*)g,
        (__attribute__((address_space(3))) void*)l, 16, 0, 0);
}

// ---------------------------------------------------------------------------
// Kernel 1: column sums  cs[g*512+d] = sum_n Z[g][n][d]   (cs pre-zeroed)
__global__ __launch_bounds__(256) void colsum_kernel(const float* __restrict__ Z,
                                                     float* __restrict__ cs) {
    int c = blockIdx.x * 256 + threadIdx.x;       // 0..2047
    int a = c >> 9;
    int d = c & 511;
    const float* p = Z + (size_t)a * GRP_ELEMS + (size_t)blockIdx.y * 512 * DD + d;
    float s = 0.f;
    #pragma unroll 8
    for (int n = 0; n < 512; ++n) s += p[(size_t)n * DD];
    atomicAdd(&cs[c], s);
}

// ---------------------------------------------------------------------------
// Kernel 2: ZbT[g][d][n] = bf16(Z[g][n][d] - mu[g][d])   (64x64 transpose tiles)
__global__ __launch_bounds__(256) void convT_kernel(const float* __restrict__ Z,
                                                    const float* __restrict__ cs,
                                                    ushort* __restrict__ ZbT) {
    __shared__ float tile[64][65];
    int g = blockIdx.z;
    int n0 = blockIdx.x * 64;
    int d0 = blockIdx.y * 64;
    int t = threadIdx.x;
    int c4 = (t & 15) * 4;
    int r = t >> 4;
    float m0 = cs[g * DD + d0 + c4 + 0] * (1.f / (float)NN);
    float m1 = cs[g * DD + d0 + c4 + 1] * (1.f / (float)NN);
    float m2 = cs[g * DD + d0 + c4 + 2] * (1.f / (float)NN);
    float m3 = cs[g * DD + d0 + c4 + 3] * (1.f / (float)NN);
    const float* Zg = Z + (size_t)g * GRP_ELEMS;
    #pragma unroll
    for (int p = 0; p < 4; ++p) {
        int rr = r + p * 16;
        float4 v = *(const float4*)&Zg[(size_t)(n0 + rr) * DD + d0 + c4];
        tile[rr][c4 + 0] = v.x - m0;
        tile[rr][c4 + 1] = v.y - m1;
        tile[rr][c4 + 2] = v.z - m2;
        tile[rr][c4 + 3] = v.w - m3;
    }
    __syncthreads();
    ushort* Og = ZbT + (size_t)g * GRP_ELEMS;
    #pragma unroll
    for (int p = 0; p < 4; ++p) {
        int dl = r + p * 16;
        int nl = c4;
        ushort4 o;
        o.x = f2b(tile[nl + 0][dl]);
        o.y = f2b(tile[nl + 1][dl]);
        o.z = f2b(tile[nl + 2][dl]);
        o.w = f2b(tile[nl + 3][dl]);
        *(ushort4*)&Og[(size_t)(d0 + dl) * NN + n0 + nl] = o;
    }
}

// ---------------------------------------------------------------------------
// Kernel 3: Zb[g][n][d] = bf16(Z - mu)  (no transpose; may alias ZbT buffer,
// launched only after syrk has consumed ZbT)
__global__ __launch_bounds__(256) void convN_kernel(const float* __restrict__ Z,
                                                    const float* __restrict__ cs,
                                                    ushort* __restrict__ Zb) {
    size_t i4 = (size_t)blockIdx.x * 256 + threadIdx.x;
    size_t base = i4 * 4;
    int g = (int)(base >> 23);
    int d = (int)(base & 511);
    float4 v = *(const float4*)&Z[base];
    const float* c = cs + g * DD + d;
    ushort4 o;
    o.x = f2b(v.x - c[0] * (1.f / (float)NN));
    o.y = f2b(v.y - c[1] * (1.f / (float)NN));
    o.z = f2b(v.z - c[2] * (1.f / (float)NN));
    o.w = f2b(v.w - c[3] * (1.f / (float)NN));
    *(ushort4*)&Zb[base] = o;
}

// ---------------------------------------------------------------------------
// Shared MFMA GEMM:  C = A * B^T, A [M][K] bf16 (lda), B [N][K] bf16 (ldb).
// 128x128 tile / workgroup, 4 waves, each wave 64x64 = 4x4 MFMA 16x16x32.
// MODE 0: syrk partial   -> outF[(chunkY*NG+g)*MAT + m*512 + n]  (fp32)
// MODE 1: plain          -> outU bf16
// MODE 2: NS update      -> outU = bf16(1.5*Cur - 0.5*invnu*acc)
// MODE 3: output gemm    -> outF = acc * nrm^(-1/4)   (group stride GRP)
template<int MODE>
__global__ __launch_bounds__(256) void gemm_bt(
    const ushort* __restrict__ Ap, const ushort* __restrict__ Bp,
    float* __restrict__ outF, ushort* __restrict__ outU,
    const ushort* __restrict__ Curp, const float* __restrict__ nrm,
    int Mtiles, int lda, int ldb, int K, size_t grpA, size_t grpB)
{
    __shared__ __align__(16) ushort As[128 * 32];
    __shared__ __align__(16) ushort Bs[128 * 32];
    const int g = blockIdx.z;
    const int tm = (blockIdx.x % Mtiles) * 128;
    const int tn = (blockIdx.x / Mtiles) * 128;
    const int kstart = blockIdx.y * K;
    const ushort* Ag = Ap + (size_t)g * grpA;
    const ushort* Bg = Bp + (size_t)g * grpB;
    const int t = threadIdx.x;
    const int wave = t >> 6, lane = t & 63;
    const int lr = lane >> 2;            // staging row within 16-row slab
    const int lc = (lane & 3) * 8;       // staging k offset (ushort)
    const int s0 = wave * 2;             // this wave's 2 slabs per operand
    const int qm = (wave & 1) * 64, qn = (wave >> 1) * 64;
    const int fm = lane & 15;            // fragment row
    const int fk = (lane >> 4) * 8;      // fragment k offset

    const ushort* a0p = Ag + (size_t)(tm + s0 * 16 + lr) * lda + lc;
    const ushort* a1p = Ag + (size_t)(tm + s0 * 16 + 16 + lr) * lda + lc;
    const ushort* b0p = Bg + (size_t)(tn + s0 * 16 + lr) * ldb + lc;
    const ushort* b1p = Bg + (size_t)(tn + s0 * 16 + 16 + lr) * ldb + lc;
    ushort* lA0 = As + s0 * 512;
    ushort* lA1 = As + s0 * 512 + 512;
    ushort* lB0 = Bs + s0 * 512;
    ushort* lB1 = Bs + s0 * 512 + 512;

    f32x4 acc[4][4] = {};
    for (int k0 = kstart; k0 < kstart + K; k0 += 32) {
        load_lds16(a0p + k0, lA0);
        load_lds16(a1p + k0, lA1);
        load_lds16(b0p + k0, lB0);
        load_lds16(b1p + k0, lB1);
        __syncthreads();                 // drains vmcnt -> LDS valid
        bf16x8 af[4], bfr[4];
        #pragma unroll
        for (int i = 0; i < 4; ++i) {
            af[i]  = *(const bf16x8*)&As[(qm + i * 16 + fm) * 32 + fk];
            bfr[i] = *(const bf16x8*)&Bs[(qn + i * 16 + fm) * 32 + fk];
        }
        #pragma unroll
        for (int i = 0; i < 4; ++i)
            #pragma unroll
            for (int j = 0; j < 4; ++j)
                acc[i][j] = __builtin_amdgcn_mfma_f32_16x16x32_bf16(
                    af[i], bfr[j], acc[i][j], 0, 0, 0);
        __syncthreads();                 // LDS reuse guard
    }

    // C/D layout (m89-verified): col = lane&15, row = (lane>>4)*4 + reg
    const int cn0 = tn + qn + fm;
    const int cm0 = tm + qm + (lane >> 4) * 4;
    if (MODE == 0) {
        float* O = outF + (size_t)(blockIdx.y * NG + g) * MAT_ELEMS;
        #pragma unroll
        for (int i = 0; i < 4; ++i)
            #pragma unroll
            for (int r = 0; r < 4; ++r) {
                size_t row = (size_t)(cm0 + i * 16 + r) * DD;
                #pragma unroll
                for (int j = 0; j < 4; ++j)
                    O[row + cn0 + j * 16] = acc[i][j][r];
            }
    } else if (MODE == 1) {
        ushort* O = outU + (size_t)g * MAT_ELEMS;
        #pragma unroll
        for (int i = 0; i < 4; ++i)
            #pragma unroll
            for (int r = 0; r < 4; ++r) {
                size_t row = (size_t)(cm0 + i * 16 + r) * DD;
                #pragma unroll
                for (int j = 0; j < 4; ++j)
                    O[row + cn0 + j * 16] = f2b(acc[i][j][r]);
            }
    } else if (MODE == 2) {
        const ushort* C = Curp + (size_t)g * MAT_ELEMS;
        ushort* O = outU + (size_t)g * MAT_ELEMS;
        float sc = 0.5f * rsqrtf(nrm[g]);        // 0.5/nu
        #pragma unroll
        for (int i = 0; i < 4; ++i)
            #pragma unroll
            for (int r = 0; r < 4; ++r) {
                size_t row = (size_t)(cm0 + i * 16 + r) * DD;
                #pragma unroll
                for (int j = 0; j < 4; ++j) {
                    size_t off = row + cn0 + j * 16;
                    O[off] = f2b(1.5f * b2f(C[off]) - sc * acc[i][j][r]);
                }
            }
    } else {
        float* O = outF + (size_t)g * GRP_ELEMS;
        float sc = rsqrtf(sqrtf(nrm[g]));        // nu^(-1/2), nu = sqrt(nrm)
        #pragma unroll
        for (int i = 0; i < 4; ++i)
            #pragma unroll
            for (int r = 0; r < 4; ++r) {
                size_t row = (size_t)(cm0 + i * 16 + r) * DD;
                #pragma unroll
                for (int j = 0; j < 4; ++j)
                    O[row + cn0 + j * 16] = sc * acc[i][j][r];
            }
    }
}

// ---------------------------------------------------------------------------
// Kernel 5: reduce split-K partials, add eps*I, emit bf16 S + Frobenius^2.
__global__ __launch_bounds__(256) void reduce_fin(const float* __restrict__ Sp,
                                                  ushort* __restrict__ Sb,
                                                  float* __restrict__ nrm) {
    int g = blockIdx.z;
    int idx = blockIdx.x * 256 + threadIdx.x;
    float v = 0.f;
    #pragma unroll
    for (int c = 0; c < KCHUNKS; ++c)
        v += Sp[(size_t)(c * NG + g) * MAT_ELEMS + idx];
    int i = idx >> 9, j = idx & 511;
    if (i == j) v += EPSV;
    Sb[(size_t)g * MAT_ELEMS + idx] = f2b(v);
    float ss = v * v;
    #pragma unroll
    for (int o = 32; o; o >>= 1) ss += __shfl_down(ss, o, 64);
    if ((threadIdx.x & 63) == 0) atomicAdd(&nrm[g], ss);
}

// ---------------------------------------------------------------------------
// Kernel 6: B1 = bf16(1.5*I - 0.5*invnu*S)   (folds NS iteration 1, B0 = I)
__global__ __launch_bounds__(256) void initB_kernel(const ushort* __restrict__ Sb,
                                                    const float* __restrict__ nrm,
                                                    ushort* __restrict__ B0) {
    int g = blockIdx.z;
    int idx = blockIdx.x * 256 + threadIdx.x;
    int i = idx >> 9, j = idx & 511;
    float invnu = rsqrtf(nrm[g]);
    size_t off = (size_t)g * MAT_ELEMS + idx;
    float v = ((i == j) ? 1.5f : 0.f) - 0.5f * invnu * b2f(Sb[off]);
    B0[off] = f2b(v);
}

// ---------------------------------------------------------------------------
extern "C" void kernel_launch(void* const* d_in, const int* in_sizes, int n_in,
                              void* d_out, int out_size, void* d_ws, size_t ws_size,
                              hipStream_t stream) {
    const float* Z = (const float*)d_in[0];
    float* out = (float*)d_out;
    float* ws = (float*)d_ws;

    float* cs  = ws;                                       // 2048 fp32
    float* nrm = ws + 2048;                                // 4 fp32
    ushort* Zbuf = (ushort*)(ws + 4096);                   // ZbT then Zb (aliased), 67 MB
    float* Spart = ws + 4096 + (NG * GRP_ELEMS / 2);       // 8*4*MAT fp32 (33.5 MB)
    ushort* Sb = (ushort*)(Spart + (size_t)KCHUNKS * NG * MAT_ELEMS);
    ushort* B0 = Sb + NG * MAT_ELEMS;
    ushort* B1 = B0 + NG * MAT_ELEMS;
    ushort* Pb = B1 + NG * MAT_ELEMS;
    ushort* Qb = Pb + NG * MAT_ELEMS;

    hipMemsetAsync(ws, 0, 2052 * sizeof(float), stream);   // cs + nrm

    colsum_kernel<<<dim3(8, 32), 256, 0, stream>>>(Z, cs);
    convT_kernel<<<dim3(256, 8, NG), 256, 0, stream>>>(Z, cs, Zbuf);

    // S partials: 4x (512,512,16384) syrk as gemm_bt over ZbT, split-K=8
    gemm_bt<0><<<dim3(16, KCHUNKS, NG), 256, 0, stream>>>(
        Zbuf, Zbuf, Spart, nullptr, nullptr, nullptr,
        4, NN, NN, NN / KCHUNKS, GRP_ELEMS, GRP_ELEMS);

    reduce_fin<<<dim3(1024, 1, NG), 256, 0, stream>>>(Spart, Sb, nrm);

    convN_kernel<<<dim3(32768), 256, 0, stream>>>(Z, cs, Zbuf);  // after syrk: alias OK

    initB_kernel<<<dim3(1024, 1, NG), 256, 0, stream>>>(Sb, nrm, B0);

    // NS iterations 2..5 (all operands symmetric -> A*B^T form everywhere)
    ushort* cur = B0; ushort* nxt = B1;
    for (int it = 0; it < 4; ++it) {
        gemm_bt<1><<<dim3(16, 1, NG), 256, 0, stream>>>(
            cur, cur, nullptr, Pb, nullptr, nullptr, 4, DD, DD, DD, MAT_ELEMS, MAT_ELEMS);
        gemm_bt<1><<<dim3(16, 1, NG), 256, 0, stream>>>(
            Pb, cur, nullptr, Qb, nullptr, nullptr, 4, DD, DD, DD, MAT_ELEMS, MAT_ELEMS);
        gemm_bt<2><<<dim3(16, 1, NG), 256, 0, stream>>>(
            Qb, Sb, nullptr, nxt, cur, nrm, 4, DD, DD, DD, MAT_ELEMS, MAT_ELEMS);
        ushort* tmp = cur; cur = nxt; nxt = tmp;
    }

    // out[g][n][i] = (Zc . Bfinal_row_i) * nrm^(-1/4)
    gemm_bt<3><<<dim3(512, 1, NG), 256, 0, stream>>>(
        Zbuf, cur, out, nullptr, nullptr, nrm, 128, DD, DD, DD, GRP_ELEMS, MAT_ELEMS);
}